// Round 4
// baseline (1731.724 us; speedup 1.0000x reference)
//
#include <hip/hip_runtime.h>
#include <hip/hip_bf16.h>
#include <math.h>

#define HID 4096
#define DH  128
#define NQH 32
#define NKVH 8
#define BB  2
#define TQ  2048
#define BT  (BB*TQ)

typedef __bf16 bf16x8 __attribute__((ext_vector_type(8)));
typedef __bf16 bf16x4 __attribute__((ext_vector_type(4)));
typedef float  f32x4  __attribute__((ext_vector_type(4)));
typedef float  f32x16 __attribute__((ext_vector_type(16)));

#define MFMA(a,b,c)   __builtin_amdgcn_mfma_f32_16x16x32_bf16(a,b,c,0,0,0)
#define MFMA32(a,b,c) __builtin_amdgcn_mfma_f32_32x32x16_bf16(a,b,c,0,0,0)

// global -> LDS direct (dwordx4). LDS dest = wave-uniform base + lane*16.
__device__ __forceinline__ void gl_lds16(const void* g, void* l) {
    __builtin_amdgcn_global_load_lds(
        (const __attribute__((address_space(1))) unsigned int*)g,
        (__attribute__((address_space(3))) unsigned int*)l, 16, 0, 0);
}

// ---------------------------------------------------------------------------
// x fp32 -> bf16 (xb lives in upper half of d_out, dead before ogemm writes).
// ---------------------------------------------------------------------------
__global__ __launch_bounds__(256) void conv_kernel(
    const float* __restrict__ x, __bf16* __restrict__ xb)
{
    const size_t i = (((size_t)blockIdx.x << 8) + threadIdx.x) << 3;
    const f32x4 f0 = *(const f32x4*)(x + i);
    const f32x4 f1 = *(const f32x4*)(x + i + 4);
    bf16x8 o;
    #pragma unroll
    for (int j = 0; j < 4; ++j) { o[j] = (__bf16)f0[j]; o[j + 4] = (__bf16)f1[j]; }
    *(bf16x8*)(xb + i) = o;
}

// ---------------------------------------------------------------------------
// QKV GEMM, m97 template: 128x128 tile, BK=64, 256 thr / 4 waves (2x2),
// 64x64 per wave, 32x32x16 MFMA, acc = 4 x f32x16.  (unchanged from R3)
// ---------------------------------------------------------------------------
__global__ __launch_bounds__(256,3) void qkv_kernel(
    const __bf16* __restrict__ xb, const float* __restrict__ wq,
    const float* __restrict__ wk,  const float* __restrict__ wv,
    const float* __restrict__ qnw, const float* __restrict__ knw,
    __bf16* __restrict__ qb, __bf16* __restrict__ kb, __bf16* __restrict__ vt)
{
    __shared__ union {
        struct { __bf16 A[128*64]; float B[64*128]; } s;   // 16 KB + 32 KB
        float Ct[64][132];                                  // 33.8 KB epilogue
    } u;

    const int bid = blockIdx.x;
    const int wg  = (bid & 7) * 192 + (bid >> 3);
    const int ct  = wg >> 5;                 // 0..47: 32 Q heads, 8 K, 8 V
    const int rt  = wg & 31;
    const int tid = threadIdx.x;
    const int lane = tid & 63;
    const int wave = tid >> 6;               // 0..3
    const int wr = wave >> 1, wc = wave & 1; // wave tile: 64x64
    const int l31 = lane & 31, hi = lane >> 5;

    const float* W; int Ncols, kind, hsel;
    if (ct < NQH)            { W = wq; Ncols = NQH*DH;  hsel = ct;          kind = 0; }
    else if (ct < NQH+NKVH)  { W = wk; Ncols = NKVH*DH; hsel = ct-NQH;      kind = 1; }
    else                     { W = wv; Ncols = NKVH*DH; hsel = ct-NQH-NKVH; kind = 2; }
    const int col0 = hsel * DH;
    const int row0 = rt << 7;

    const int arow = (wave << 5) + (lane >> 3);
    const int acol = (((lane & 7) ^ ((lane >> 3) & 7)) << 3);
    const __bf16* aSrc = xb + (size_t)(row0 + arow) * HID + acol;

    const int bk  = (wave << 4) + (lane >> 5);
    const int bn  = (lane & 31) << 2;
    const float* bSrc = W + (size_t)bk * Ncols + col0 + bn;

    const int aBase0 = ((wr << 6) + l31) << 6;
    const int aBase1 = aBase0 + (32 << 6);
    const int axor   = l31 & 7;
    const int bCol   = (wc << 6) + l31;

    f32x16 acc00 = {0.f,0.f,0.f,0.f,0.f,0.f,0.f,0.f,0.f,0.f,0.f,0.f,0.f,0.f,0.f,0.f};
    f32x16 acc01 = acc00, acc10 = acc00, acc11 = acc00;

    for (int k0 = 0; k0 < HID; k0 += 64) {
        __syncthreads();
        #pragma unroll
        for (int i = 0; i < 4; ++i)
            gl_lds16(aSrc + k0 + (size_t)(i << 3) * HID,
                     &u.s.A[((wave << 5) + (i << 3)) << 6]);
        #pragma unroll
        for (int i = 0; i < 8; ++i)
            gl_lds16(bSrc + (size_t)(k0 + (i << 1)) * Ncols,
                     &u.s.B[((wave << 4) + (i << 1)) << 7]);
        __syncthreads();

        #pragma unroll
        for (int kr = 0; kr < 4; ++kr) {
            const int ag = (((kr << 1) + hi) ^ axor) << 3;
            bf16x8 fa0 = *(const bf16x8*)&u.s.A[aBase0 + ag];
            bf16x8 fa1 = *(const bf16x8*)&u.s.A[aBase1 + ag];
            const int kb8 = (kr << 4) + (hi << 3);
            bf16x8 fb0, fb1;
            #pragma unroll
            for (int j = 0; j < 8; ++j) {
                fb0[j] = (__bf16)u.s.B[((kb8 + j) << 7) + bCol];
                fb1[j] = (__bf16)u.s.B[((kb8 + j) << 7) + bCol + 32];
            }
            acc00 = MFMA32(fa0, fb0, acc00);
            acc01 = MFMA32(fa0, fb1, acc01);
            acc10 = MFMA32(fa1, fb0, acc10);
            acc11 = MFMA32(fa1, fb1, acc11);
        }
    }

    const int bidx = row0 >> 11;
    #pragma unroll
    for (int pass = 0; pass < 2; ++pass) {
        __syncthreads();
        if (wr == pass) {
            #pragma unroll
            for (int rc = 0; rc < 4; ++rc) {
                const f32x16 a = (rc == 0) ? acc00 : (rc == 1) ? acc01
                               : (rc == 2) ? acc10 : acc11;
                const int rr = (rc >> 1), cc = (rc & 1);
                #pragma unroll
                for (int r = 0; r < 16; ++r) {
                    const int row = (rr << 5) + (r & 3) + ((r >> 2) << 3) + (hi << 2);
                    u.Ct[row][(wc << 6) + (cc << 5) + l31] = a[r];
                }
            }
        }
        __syncthreads();
        if (kind == 2) {
            const int d  = tid >> 1;
            const int t0 = (tid & 1) << 5;
            __bf16* dst = vt + ((size_t)(bidx*NKVH + hsel)*DH + d)*TQ
                             + (row0 & (TQ-1)) + (pass << 6) + t0;
            #pragma unroll
            for (int c = 0; c < 8; ++c) {
                bf16x4 o;
                #pragma unroll
                for (int i = 0; i < 4; ++i) o[i] = (__bf16)u.Ct[t0 + (c << 2) + i][d];
                *(bf16x4*)(dst + (c << 2)) = o;
            }
        } else {
            const int r  = tid >> 2;
            const int c0 = (tid & 3) << 5;
            float ss = 0.f;
            #pragma unroll
            for (int i = 0; i < 32; ++i) { const float v = u.Ct[r][c0 + i]; ss += v*v; }
            ss += __shfl_xor(ss, 1); ss += __shfl_xor(ss, 2);
            const float inv = rsqrtf(ss * (1.0f/DH) + 1e-6f);
            const float* nw = kind ? knw : qnw;
            const int tpos = (row0 & (TQ-1)) + (pass << 6) + r;
            __bf16* dst = (kind == 0)
                ? qb + ((size_t)(bidx*NQH  + hsel)*TQ + tpos)*DH + c0
                : kb + ((size_t)(bidx*NKVH + hsel)*TQ + tpos)*DH + c0;
            #pragma unroll
            for (int cc = 0; cc < 8; ++cc) {
                bf16x4 o;
                #pragma unroll
                for (int i = 0; i < 4; ++i) {
                    const int c = c0 + (cc << 2) + i;
                    const float nv = nw[c]      * u.Ct[r][c]      * inv;
                    const float pv = nw[c ^ 64] * u.Ct[r][c ^ 64] * inv;
                    const float ang = (float)tpos * exp2f(-0.31143075895f * (float)(c & 63));
                    float sn, cs; sincosf(ang, &sn, &cs);
                    o[i] = (__bf16)((c < 64) ? (nv*cs - pv*sn) : (nv*cs + pv*sn));
                }
                *(bf16x4*)(dst + (cc << 2)) = o;
            }
        }
    }
}

// ---------------------------------------------------------------------------
// Flash attention, causal, GQA. 4 waves/block, each an independent 16-row
// Q tile (own Pl slice, no block barriers -> no workgroup-cap stall).
// Defer-max (THR=8): steady-state softmax has NO cross-lane reduce; the
// l-sum is a per-lane partial reduced once after the kt loop.
// ---------------------------------------------------------------------------
__global__ __launch_bounds__(256) void attn_kernel(
    const __bf16* __restrict__ qb, const __bf16* __restrict__ kb,
    const __bf16* __restrict__ vt, __bf16* __restrict__ ab)
{
    const int tid  = threadIdx.x;
    const int wave = tid >> 6;
    const int lane = tid & 63;
    const int qt = (blockIdx.x << 2) + wave;
    const int bh = blockIdx.y;
    const int b = bh >> 5, h = bh & 31, hk = h >> 2;
    const int m16 = lane & 15, quad = lane >> 4;

    const __bf16* qp = qb + (size_t)(b*NQH  + h )*TQ*DH;
    const __bf16* kp = kb + (size_t)(b*NKVH + hk)*TQ*DH;
    const __bf16* vp = vt + (size_t)(b*NKVH + hk)*DH*TQ;   // [d][t]

    const int q0 = qt << 4;
    bf16x8 aq[4];
    #pragma unroll
    for (int ks = 0; ks < 4; ++ks)
        aq[ks] = *(const bf16x8*)(qp + (size_t)(q0 + m16)*DH + (ks << 5) + (quad << 3));

    f32x4 o[8];
    #pragma unroll
    for (int cc = 0; cc < 8; ++cc) o[cc] = (f32x4){0.f,0.f,0.f,0.f};
    float mrow[4] = {-1e30f,-1e30f,-1e30f,-1e30f};
    float lsum[4] = {0.f,0.f,0.f,0.f};      // per-lane partial row-sum

    __shared__ alignas(16) __bf16 Pl[4][16][40];   // per-wave slice
    const float scale = 0.08838834764831845f;      // 1/sqrt(128)

    const int ktmax = (q0 + 15) >> 5;
    for (int kt = 0; kt <= ktmax; ++kt) {
        const int k0 = kt << 5;
        f32x4 s0 = {0.f,0.f,0.f,0.f}, s1 = {0.f,0.f,0.f,0.f};
        #pragma unroll
        for (int ks = 0; ks < 4; ++ks) {
            bf16x8 b0 = *(const bf16x8*)(kp + (size_t)(k0 + m16)*DH      + (ks << 5) + (quad << 3));
            bf16x8 b1 = *(const bf16x8*)(kp + (size_t)(k0 + 16 + m16)*DH + (ks << 5) + (quad << 3));
            s0 = MFMA(aq[ks], b0, s0);
            s1 = MFMA(aq[ks], b1, s1);
        }
        float a_[4], b_[4];
        bool need = false;
        #pragma unroll
        for (int r = 0; r < 4; ++r) {
            const int qg = q0 + (quad << 2) + r;
            const int kg = k0 + m16;
            a_[r] = (kg      <= qg) ? s0[r]*scale : -1e30f;
            b_[r] = (kg + 16 <= qg) ? s1[r]*scale : -1e30f;
            need |= (fmaxf(a_[r], b_[r]) > mrow[r] + 8.0f);
        }
        if (__any(need)) {                   // rescale path (rare after tile 0)
            #pragma unroll
            for (int r = 0; r < 4; ++r) {
                float t = fmaxf(a_[r], b_[r]);
                t = fmaxf(t, __shfl_xor(t, 1)); t = fmaxf(t, __shfl_xor(t, 2));
                t = fmaxf(t, __shfl_xor(t, 4)); t = fmaxf(t, __shfl_xor(t, 8));
                const float mn = fmaxf(mrow[r], t);
                const float al = __expf(mrow[r] - mn);
                lsum[r] *= al;
                mrow[r] = mn;
                #pragma unroll
                for (int cc = 0; cc < 8; ++cc) o[cc][r] *= al;
            }
        }
        #pragma unroll
        for (int r = 0; r < 4; ++r) {        // P bounded by e^8: bf16-safe
            const float p0 = __expf(a_[r] - mrow[r]);
            const float p1 = __expf(b_[r] - mrow[r]);
            lsum[r] += p0 + p1;
            Pl[wave][(quad << 2) + r][m16]      = (__bf16)p0;
            Pl[wave][(quad << 2) + r][m16 + 16] = (__bf16)p1;
        }
        asm volatile("s_waitcnt lgkmcnt(0)" ::: "memory");   // wave-local P fence
        const bf16x8 pf = *(const bf16x8*)&Pl[wave][m16][quad << 3];
        #pragma unroll
        for (int cc = 0; cc < 8; ++cc) {
            bf16x8 vf = *(const bf16x8*)(vp + (size_t)((cc << 4) + m16)*TQ + k0 + (quad << 3));
            o[cc] = MFMA(pf, vf, o[cc]);
        }
    }

    #pragma unroll
    for (int r = 0; r < 4; ++r) {
        float ls = lsum[r];
        ls += __shfl_xor(ls, 1); ls += __shfl_xor(ls, 2);
        ls += __shfl_xor(ls, 4); ls += __shfl_xor(ls, 8);
        const float invl = 1.0f / ls;
        const int t = q0 + (quad << 2) + r;
        __bf16* dst = ab + (size_t)(b*TQ + t)*(NQH*DH) + h*DH + m16;
        #pragma unroll
        for (int cc = 0; cc < 8; ++cc)
            dst[cc << 4] = (__bf16)(o[cc][r] * invl);
    }
}

// ---------------------------------------------------------------------------
// Output GEMM: ab(bf16)[BT x 4096] @ wo(fp32)[4096 x 4096] -> out fp32.
// (unchanged from R3)
// ---------------------------------------------------------------------------
__global__ __launch_bounds__(256,3) void ogemm_kernel(
    const __bf16* __restrict__ Am, const float* __restrict__ W,
    float* __restrict__ out)
{
    __shared__ struct { __bf16 A[128*64]; float B[64*128]; } s;

    const int bid = blockIdx.x;
    const int wg  = (bid & 7) * 128 + (bid >> 3);
    const int ct  = wg >> 5, rt = wg & 31;
    const int tid = threadIdx.x;
    const int lane = tid & 63;
    const int wave = tid >> 6;
    const int wr = wave >> 1, wc = wave & 1;
    const int l31 = lane & 31, hi = lane >> 5;
    const int col0 = ct << 7;
    const int row0 = rt << 7;

    const int arow = (wave << 5) + (lane >> 3);
    const int acol = (((lane & 7) ^ ((lane >> 3) & 7)) << 3);
    const __bf16* aSrc = Am + (size_t)(row0 + arow) * HID + acol;

    const int bk  = (wave << 4) + (lane >> 5);
    const int bn  = (lane & 31) << 2;
    const float* bSrc = W + (size_t)bk * HID + col0 + bn;

    const int aBase0 = ((wr << 6) + l31) << 6;
    const int aBase1 = aBase0 + (32 << 6);
    const int axor   = l31 & 7;
    const int bCol   = (wc << 6) + l31;

    f32x16 acc00 = {0.f,0.f,0.f,0.f,0.f,0.f,0.f,0.f,0.f,0.f,0.f,0.f,0.f,0.f,0.f,0.f};
    f32x16 acc01 = acc00, acc10 = acc00, acc11 = acc00;

    for (int k0 = 0; k0 < HID; k0 += 64) {
        __syncthreads();
        #pragma unroll
        for (int i = 0; i < 4; ++i)
            gl_lds16(aSrc + k0 + (size_t)(i << 3) * HID,
                     &s.A[((wave << 5) + (i << 3)) << 6]);
        #pragma unroll
        for (int i = 0; i < 8; ++i)
            gl_lds16(bSrc + (size_t)(k0 + (i << 1)) * HID,
                     &s.B[((wave << 4) + (i << 1)) << 7]);
        __syncthreads();

        #pragma unroll
        for (int kr = 0; kr < 4; ++kr) {
            const int ag = (((kr << 1) + hi) ^ axor) << 3;
            bf16x8 fa0 = *(const bf16x8*)&s.A[aBase0 + ag];
            bf16x8 fa1 = *(const bf16x8*)&s.A[aBase1 + ag];
            const int kb8 = (kr << 4) + (hi << 3);
            bf16x8 fb0, fb1;
            #pragma unroll
            for (int j = 0; j < 8; ++j) {
                fb0[j] = (__bf16)s.B[((kb8 + j) << 7) + bCol];
                fb1[j] = (__bf16)s.B[((kb8 + j) << 7) + bCol + 32];
            }
            acc00 = MFMA32(fa0, fb0, acc00);
            acc01 = MFMA32(fa0, fb1, acc01);
            acc10 = MFMA32(fa1, fb0, acc10);
            acc11 = MFMA32(fa1, fb1, acc11);
        }
    }

    #pragma unroll
    for (int rc = 0; rc < 4; ++rc) {
        const f32x16 a = (rc == 0) ? acc00 : (rc == 1) ? acc01
                       : (rc == 2) ? acc10 : acc11;
        const int rr = (rc >> 1), cc = (rc & 1);
        #pragma unroll
        for (int r = 0; r < 16; ++r) {
            const int row = row0 + (wr << 6) + (rr << 5)
                          + (r & 3) + ((r >> 2) << 3) + (hi << 2);
            out[(size_t)row * HID + col0 + (wc << 6) + (cc << 5) + l31] = a[r];
        }
    }
}

extern "C" void kernel_launch(void* const* d_in, const int* in_sizes, int n_in,
                              void* d_out, int out_size, void* d_ws, size_t ws_size,
                              hipStream_t stream)
{
    const float* x   = (const float*)d_in[0];
    const float* wq  = (const float*)d_in[1];
    const float* wk  = (const float*)d_in[2];
    const float* wv  = (const float*)d_in[3];
    const float* wo  = (const float*)d_in[4];
    const float* qnw = (const float*)d_in[5];
    const float* knw = (const float*)d_in[6];
    float* out = (float*)d_out;

    // d_out (67 MB fp32) double-duty:
    //   lower half: qb (bf16) - read by attn strictly before ogemm writes out.
    //   upper half: xb (bf16) - read by qkv, dead before attn/ogemm run.
    __bf16* qb = (__bf16*)d_out;                        // [B][32][T][128]  33.5 MB
    __bf16* xb = (__bf16*)d_out + (size_t)BB*NQH*TQ*DH; // [BT][4096]      33.5 MB
    __bf16* kb = (__bf16*)d_ws;                         // [B][8][T][128]    8.4 MB
    __bf16* vt = kb + (size_t)BB*NKVH*TQ*DH;            // [B][8][128][T]    8.4 MB
    __bf16* ab = vt + (size_t)BB*NKVH*TQ*DH;            // [B][T][4096]     33.5 MB
    const size_t need = ((size_t)BB*NKVH*TQ*DH*2 + (size_t)BB*TQ*NQH*DH)*sizeof(__bf16);
    if (ws_size < need) return;   // deterministic no-op -> diagnosable absmax

    conv_kernel<<<dim3((BT*HID)/2048), 256, 0, stream>>>(x, xb);
    qkv_kernel<<<dim3(48*32), 256, 0, stream>>>(xb, wq, wk, wv, qnw, knw, qb, kb, vt);
    attn_kernel<<<dim3(TQ/64, BB*NQH), 256, 0, stream>>>(qb, kb, vt, ab);
    ogemm_kernel<<<dim3(32*32), 256, 0, stream>>>(ab, wo, out);
}

// Round 5
// 1307.079 us; speedup vs baseline: 1.3249x; 1.3249x over previous
//
#include <hip/hip_runtime.h>
#include <hip/hip_bf16.h>
#include <math.h>

#define HID 4096
#define DH  128
#define NQH 32
#define NKVH 8
#define BB  2
#define TQ  2048
#define BT  (BB*TQ)

typedef __bf16 bf16x8 __attribute__((ext_vector_type(8)));
typedef __bf16 bf16x4 __attribute__((ext_vector_type(4)));
typedef float  f32x4  __attribute__((ext_vector_type(4)));
typedef float  f32x16 __attribute__((ext_vector_type(16)));

#define MFMA(a,b,c)   __builtin_amdgcn_mfma_f32_16x16x32_bf16(a,b,c,0,0,0)
#define MFMA32(a,b,c) __builtin_amdgcn_mfma_f32_32x32x16_bf16(a,b,c,0,0,0)

// global -> LDS direct (dwordx4). LDS dest = wave-uniform base + lane*16.
__device__ __forceinline__ void gl_lds16(const void* g, void* l) {
    __builtin_amdgcn_global_load_lds(
        (const __attribute__((address_space(1))) unsigned int*)g,
        (__attribute__((address_space(3))) unsigned int*)l, 16, 0, 0);
}

// ---------------------------------------------------------------------------
// x fp32 -> bf16 (xb lives in upper half of d_out, dead before ogemm writes).
// ---------------------------------------------------------------------------
__global__ __launch_bounds__(256) void conv_kernel(
    const float* __restrict__ x, __bf16* __restrict__ xb)
{
    const size_t i = (((size_t)blockIdx.x << 8) + threadIdx.x) << 3;
    const f32x4 f0 = *(const f32x4*)(x + i);
    const f32x4 f1 = *(const f32x4*)(x + i + 4);
    bf16x8 o;
    #pragma unroll
    for (int j = 0; j < 4; ++j) { o[j] = (__bf16)f0[j]; o[j + 4] = (__bf16)f1[j]; }
    *(bf16x8*)(xb + i) = o;
}

// ---------------------------------------------------------------------------
// QKV GEMM, m97 template: 128x128 tile, BK=64, 256 thr / 4 waves (2x2),
// 64x64 per wave, 32x32x16 MFMA, acc = 4 x f32x16.  (unchanged from R3)
// ---------------------------------------------------------------------------
__global__ __launch_bounds__(256,3) void qkv_kernel(
    const __bf16* __restrict__ xb, const float* __restrict__ wq,
    const float* __restrict__ wk,  const float* __restrict__ wv,
    const float* __restrict__ qnw, const float* __restrict__ knw,
    __bf16* __restrict__ qb, __bf16* __restrict__ kb, __bf16* __restrict__ vt)
{
    __shared__ union {
        struct { __bf16 A[128*64]; float B[64*128]; } s;   // 16 KB + 32 KB
        float Ct[64][132];                                  // 33.8 KB epilogue
    } u;

    const int bid = blockIdx.x;
    const int wg  = (bid & 7) * 192 + (bid >> 3);
    const int ct  = wg >> 5;                 // 0..47: 32 Q heads, 8 K, 8 V
    const int rt  = wg & 31;
    const int tid = threadIdx.x;
    const int lane = tid & 63;
    const int wave = tid >> 6;               // 0..3
    const int wr = wave >> 1, wc = wave & 1; // wave tile: 64x64
    const int l31 = lane & 31, hi = lane >> 5;

    const float* W; int Ncols, kind, hsel;
    if (ct < NQH)            { W = wq; Ncols = NQH*DH;  hsel = ct;          kind = 0; }
    else if (ct < NQH+NKVH)  { W = wk; Ncols = NKVH*DH; hsel = ct-NQH;      kind = 1; }
    else                     { W = wv; Ncols = NKVH*DH; hsel = ct-NQH-NKVH; kind = 2; }
    const int col0 = hsel * DH;
    const int row0 = rt << 7;

    const int arow = (wave << 5) + (lane >> 3);
    const int acol = (((lane & 7) ^ ((lane >> 3) & 7)) << 3);
    const __bf16* aSrc = xb + (size_t)(row0 + arow) * HID + acol;

    const int bk  = (wave << 4) + (lane >> 5);
    const int bn  = (lane & 31) << 2;
    const float* bSrc = W + (size_t)bk * Ncols + col0 + bn;

    const int aBase0 = ((wr << 6) + l31) << 6;
    const int aBase1 = aBase0 + (32 << 6);
    const int axor   = l31 & 7;
    const int bCol   = (wc << 6) + l31;

    f32x16 acc00 = {0.f,0.f,0.f,0.f,0.f,0.f,0.f,0.f,0.f,0.f,0.f,0.f,0.f,0.f,0.f,0.f};
    f32x16 acc01 = acc00, acc10 = acc00, acc11 = acc00;

    for (int k0 = 0; k0 < HID; k0 += 64) {
        __syncthreads();
        #pragma unroll
        for (int i = 0; i < 4; ++i)
            gl_lds16(aSrc + k0 + (size_t)(i << 3) * HID,
                     &u.s.A[((wave << 5) + (i << 3)) << 6]);
        #pragma unroll
        for (int i = 0; i < 8; ++i)
            gl_lds16(bSrc + (size_t)(k0 + (i << 1)) * Ncols,
                     &u.s.B[((wave << 4) + (i << 1)) << 7]);
        __syncthreads();

        #pragma unroll
        for (int kr = 0; kr < 4; ++kr) {
            const int ag = (((kr << 1) + hi) ^ axor) << 3;
            bf16x8 fa0 = *(const bf16x8*)&u.s.A[aBase0 + ag];
            bf16x8 fa1 = *(const bf16x8*)&u.s.A[aBase1 + ag];
            const int kb8 = (kr << 4) + (hi << 3);
            bf16x8 fb0, fb1;
            #pragma unroll
            for (int j = 0; j < 8; ++j) {
                fb0[j] = (__bf16)u.s.B[((kb8 + j) << 7) + bCol];
                fb1[j] = (__bf16)u.s.B[((kb8 + j) << 7) + bCol + 32];
            }
            acc00 = MFMA32(fa0, fb0, acc00);
            acc01 = MFMA32(fa0, fb1, acc01);
            acc10 = MFMA32(fa1, fb0, acc10);
            acc11 = MFMA32(fa1, fb1, acc11);
        }
    }

    const int bidx = row0 >> 11;
    #pragma unroll
    for (int pass = 0; pass < 2; ++pass) {
        __syncthreads();
        if (wr == pass) {
            #pragma unroll
            for (int rc = 0; rc < 4; ++rc) {
                const f32x16 a = (rc == 0) ? acc00 : (rc == 1) ? acc01
                               : (rc == 2) ? acc10 : acc11;
                const int rr = (rc >> 1), cc = (rc & 1);
                #pragma unroll
                for (int r = 0; r < 16; ++r) {
                    const int row = (rr << 5) + (r & 3) + ((r >> 2) << 3) + (hi << 2);
                    u.Ct[row][(wc << 6) + (cc << 5) + l31] = a[r];
                }
            }
        }
        __syncthreads();
        if (kind == 2) {
            const int d  = tid >> 1;
            const int t0 = (tid & 1) << 5;
            __bf16* dst = vt + ((size_t)(bidx*NKVH + hsel)*DH + d)*TQ
                             + (row0 & (TQ-1)) + (pass << 6) + t0;
            #pragma unroll
            for (int c = 0; c < 8; ++c) {
                bf16x4 o;
                #pragma unroll
                for (int i = 0; i < 4; ++i) o[i] = (__bf16)u.Ct[t0 + (c << 2) + i][d];
                *(bf16x4*)(dst + (c << 2)) = o;
            }
        } else {
            const int r  = tid >> 2;
            const int c0 = (tid & 3) << 5;
            float ss = 0.f;
            #pragma unroll
            for (int i = 0; i < 32; ++i) { const float v = u.Ct[r][c0 + i]; ss += v*v; }
            ss += __shfl_xor(ss, 1); ss += __shfl_xor(ss, 2);
            const float inv = rsqrtf(ss * (1.0f/DH) + 1e-6f);
            const float* nw = kind ? knw : qnw;
            const int tpos = (row0 & (TQ-1)) + (pass << 6) + r;
            __bf16* dst = (kind == 0)
                ? qb + ((size_t)(bidx*NQH  + hsel)*TQ + tpos)*DH + c0
                : kb + ((size_t)(bidx*NKVH + hsel)*TQ + tpos)*DH + c0;
            #pragma unroll
            for (int cc = 0; cc < 8; ++cc) {
                bf16x4 o;
                #pragma unroll
                for (int i = 0; i < 4; ++i) {
                    const int c = c0 + (cc << 2) + i;
                    const float nv = nw[c]      * u.Ct[r][c]      * inv;
                    const float pv = nw[c ^ 64] * u.Ct[r][c ^ 64] * inv;
                    const float ang = (float)tpos * exp2f(-0.31143075895f * (float)(c & 63));
                    float sn, cs; sincosf(ang, &sn, &cs);
                    o[i] = (__bf16)((c < 64) ? (nv*cs - pv*sn) : (nv*cs + pv*sn));
                }
                *(bf16x4*)(dst + (cc << 2)) = o;
            }
        }
    }
}

// ---------------------------------------------------------------------------
// Flash attention, causal, GQA. 4 waves/block; each wave processes the
// COMPLEMENTARY q-tile pair (i, 127-i) -> every wave has ~65 K-tiles of
// work (causal load balancing: no short blocks, no long-tail drain).
// Defer-max (THR=8): steady-state softmax has NO cross-lane reduce; the
// l-sum is a per-lane partial reduced once per tile after the kt loop.
// ---------------------------------------------------------------------------
__global__ __launch_bounds__(256) void attn_kernel(
    const __bf16* __restrict__ qb, const __bf16* __restrict__ kb,
    const __bf16* __restrict__ vt, __bf16* __restrict__ ab)
{
    const int tid  = threadIdx.x;
    const int wave = tid >> 6;
    const int lane = tid & 63;
    const int pairIdx = (blockIdx.x << 2) + wave;   // 0..63
    const int bh = blockIdx.y;
    const int b = bh >> 5, h = bh & 31, hk = h >> 2;
    const int m16 = lane & 15, quad = lane >> 4;

    const __bf16* qp = qb + (size_t)(b*NQH  + h )*TQ*DH;
    const __bf16* kp = kb + (size_t)(b*NKVH + hk)*TQ*DH;
    const __bf16* vp = vt + (size_t)(b*NKVH + hk)*DH*TQ;   // [d][t]

    __shared__ alignas(16) __bf16 Pl[4][16][40];   // per-wave slice
    const float scale = 0.08838834764831845f;      // 1/sqrt(128)

    for (int half = 0; half < 2; ++half) {
        const int qt = half ? (TQ/16 - 1 - pairIdx) : pairIdx;
        const int q0 = qt << 4;

        bf16x8 aq[4];
        #pragma unroll
        for (int ks = 0; ks < 4; ++ks)
            aq[ks] = *(const bf16x8*)(qp + (size_t)(q0 + m16)*DH + (ks << 5) + (quad << 3));

        f32x4 o[8];
        #pragma unroll
        for (int cc = 0; cc < 8; ++cc) o[cc] = (f32x4){0.f,0.f,0.f,0.f};
        float mrow[4] = {-1e30f,-1e30f,-1e30f,-1e30f};
        float lsum[4] = {0.f,0.f,0.f,0.f};

        const int ktmax = (q0 + 15) >> 5;
        for (int kt = 0; kt <= ktmax; ++kt) {
            const int k0 = kt << 5;
            f32x4 s0 = {0.f,0.f,0.f,0.f}, s1 = {0.f,0.f,0.f,0.f};
            #pragma unroll
            for (int ks = 0; ks < 4; ++ks) {
                bf16x8 b0 = *(const bf16x8*)(kp + (size_t)(k0 + m16)*DH      + (ks << 5) + (quad << 3));
                bf16x8 b1 = *(const bf16x8*)(kp + (size_t)(k0 + 16 + m16)*DH + (ks << 5) + (quad << 3));
                s0 = MFMA(aq[ks], b0, s0);
                s1 = MFMA(aq[ks], b1, s1);
            }
            float a_[4], b_[4];
            bool need = false;
            #pragma unroll
            for (int r = 0; r < 4; ++r) {
                const int qg = q0 + (quad << 2) + r;
                const int kg = k0 + m16;
                a_[r] = (kg      <= qg) ? s0[r]*scale : -1e30f;
                b_[r] = (kg + 16 <= qg) ? s1[r]*scale : -1e30f;
                need |= (fmaxf(a_[r], b_[r]) > mrow[r] + 8.0f);
            }
            if (__any(need)) {               // rescale path (rare after tile 0)
                #pragma unroll
                for (int r = 0; r < 4; ++r) {
                    float t = fmaxf(a_[r], b_[r]);
                    t = fmaxf(t, __shfl_xor(t, 1)); t = fmaxf(t, __shfl_xor(t, 2));
                    t = fmaxf(t, __shfl_xor(t, 4)); t = fmaxf(t, __shfl_xor(t, 8));
                    const float mn = fmaxf(mrow[r], t);
                    const float al = __expf(mrow[r] - mn);
                    lsum[r] *= al;
                    mrow[r] = mn;
                    #pragma unroll
                    for (int cc = 0; cc < 8; ++cc) o[cc][r] *= al;
                }
            }
            #pragma unroll
            for (int r = 0; r < 4; ++r) {    // P bounded by e^8: bf16-safe
                const float p0 = __expf(a_[r] - mrow[r]);
                const float p1 = __expf(b_[r] - mrow[r]);
                lsum[r] += p0 + p1;
                Pl[wave][(quad << 2) + r][m16]      = (__bf16)p0;
                Pl[wave][(quad << 2) + r][m16 + 16] = (__bf16)p1;
            }
            asm volatile("s_waitcnt lgkmcnt(0)" ::: "memory");  // wave-local P fence
            __builtin_amdgcn_sched_barrier(0);                  // no MFMA hoist past fence
            const bf16x8 pf = *(const bf16x8*)&Pl[wave][m16][quad << 3];
            #pragma unroll
            for (int cc = 0; cc < 8; ++cc) {
                bf16x8 vf = *(const bf16x8*)(vp + (size_t)((cc << 4) + m16)*TQ + k0 + (quad << 3));
                o[cc] = MFMA(pf, vf, o[cc]);
            }
        }

        #pragma unroll
        for (int r = 0; r < 4; ++r) {
            float ls = lsum[r];
            ls += __shfl_xor(ls, 1); ls += __shfl_xor(ls, 2);
            ls += __shfl_xor(ls, 4); ls += __shfl_xor(ls, 8);
            const float invl = 1.0f / ls;
            const int t = q0 + (quad << 2) + r;
            __bf16* dst = ab + (size_t)(b*TQ + t)*(NQH*DH) + h*DH + m16;
            #pragma unroll
            for (int cc = 0; cc < 8; ++cc)
                dst[cc << 4] = (__bf16)(o[cc][r] * invl);
        }
    }
}

// ---------------------------------------------------------------------------
// Output GEMM: ab(bf16)[BT x 4096] @ wo(fp32)[4096 x 4096] -> out fp32.
// (unchanged from R3)
// ---------------------------------------------------------------------------
__global__ __launch_bounds__(256,3) void ogemm_kernel(
    const __bf16* __restrict__ Am, const float* __restrict__ W,
    float* __restrict__ out)
{
    __shared__ struct { __bf16 A[128*64]; float B[64*128]; } s;

    const int bid = blockIdx.x;
    const int wg  = (bid & 7) * 128 + (bid >> 3);
    const int ct  = wg >> 5, rt = wg & 31;
    const int tid = threadIdx.x;
    const int lane = tid & 63;
    const int wave = tid >> 6;
    const int wr = wave >> 1, wc = wave & 1;
    const int l31 = lane & 31, hi = lane >> 5;
    const int col0 = ct << 7;
    const int row0 = rt << 7;

    const int arow = (wave << 5) + (lane >> 3);
    const int acol = (((lane & 7) ^ ((lane >> 3) & 7)) << 3);
    const __bf16* aSrc = Am + (size_t)(row0 + arow) * HID + acol;

    const int bk  = (wave << 4) + (lane >> 5);
    const int bn  = (lane & 31) << 2;
    const float* bSrc = W + (size_t)bk * HID + col0 + bn;

    const int aBase0 = ((wr << 6) + l31) << 6;
    const int aBase1 = aBase0 + (32 << 6);
    const int axor   = l31 & 7;
    const int bCol   = (wc << 6) + l31;

    f32x16 acc00 = {0.f,0.f,0.f,0.f,0.f,0.f,0.f,0.f,0.f,0.f,0.f,0.f,0.f,0.f,0.f,0.f};
    f32x16 acc01 = acc00, acc10 = acc00, acc11 = acc00;

    for (int k0 = 0; k0 < HID; k0 += 64) {
        __syncthreads();
        #pragma unroll
        for (int i = 0; i < 4; ++i)
            gl_lds16(aSrc + k0 + (size_t)(i << 3) * HID,
                     &s.A[((wave << 5) + (i << 3)) << 6]);
        #pragma unroll
        for (int i = 0; i < 8; ++i)
            gl_lds16(bSrc + (size_t)(k0 + (i << 1)) * HID,
                     &s.B[((wave << 4) + (i << 1)) << 7]);
        __syncthreads();

        #pragma unroll
        for (int kr = 0; kr < 4; ++kr) {
            const int ag = (((kr << 1) + hi) ^ axor) << 3;
            bf16x8 fa0 = *(const bf16x8*)&s.A[aBase0 + ag];
            bf16x8 fa1 = *(const bf16x8*)&s.A[aBase1 + ag];
            const int kb8 = (kr << 4) + (hi << 3);
            bf16x8 fb0, fb1;
            #pragma unroll
            for (int j = 0; j < 8; ++j) {
                fb0[j] = (__bf16)s.B[((kb8 + j) << 7) + bCol];
                fb1[j] = (__bf16)s.B[((kb8 + j) << 7) + bCol + 32];
            }
            acc00 = MFMA32(fa0, fb0, acc00);
            acc01 = MFMA32(fa0, fb1, acc01);
            acc10 = MFMA32(fa1, fb0, acc10);
            acc11 = MFMA32(fa1, fb1, acc11);
        }
    }

    #pragma unroll
    for (int rc = 0; rc < 4; ++rc) {
        const f32x16 a = (rc == 0) ? acc00 : (rc == 1) ? acc01
                       : (rc == 2) ? acc10 : acc11;
        const int rr = (rc >> 1), cc = (rc & 1);
        #pragma unroll
        for (int r = 0; r < 16; ++r) {
            const int row = row0 + (wr << 6) + (rr << 5)
                          + (r & 3) + ((r >> 2) << 3) + (hi << 2);
            out[(size_t)row * HID + col0 + (wc << 6) + (cc << 5) + l31] = a[r];
        }
    }
}

extern "C" void kernel_launch(void* const* d_in, const int* in_sizes, int n_in,
                              void* d_out, int out_size, void* d_ws, size_t ws_size,
                              hipStream_t stream)
{
    const float* x   = (const float*)d_in[0];
    const float* wq  = (const float*)d_in[1];
    const float* wk  = (const float*)d_in[2];
    const float* wv  = (const float*)d_in[3];
    const float* wo  = (const float*)d_in[4];
    const float* qnw = (const float*)d_in[5];
    const float* knw = (const float*)d_in[6];
    float* out = (float*)d_out;

    // d_out (67 MB fp32) double-duty:
    //   lower half: qb (bf16) - read by attn strictly before ogemm writes out.
    //   upper half: xb (bf16) - read by qkv, dead before attn/ogemm run.
    __bf16* qb = (__bf16*)d_out;                        // [B][32][T][128]  33.5 MB
    __bf16* xb = (__bf16*)d_out + (size_t)BB*NQH*TQ*DH; // [BT][4096]      33.5 MB
    __bf16* kb = (__bf16*)d_ws;                         // [B][8][T][128]    8.4 MB
    __bf16* vt = kb + (size_t)BB*NKVH*TQ*DH;            // [B][8][128][T]    8.4 MB
    __bf16* ab = vt + (size_t)BB*NKVH*TQ*DH;            // [B][T][4096]     33.5 MB
    const size_t need = ((size_t)BB*NKVH*TQ*DH*2 + (size_t)BB*TQ*NQH*DH)*sizeof(__bf16);
    if (ws_size < need) return;   // deterministic no-op -> diagnosable absmax

    conv_kernel<<<dim3((BT*HID)/2048), 256, 0, stream>>>(x, xb);
    qkv_kernel<<<dim3(48*32), 256, 0, stream>>>(xb, wq, wk, wv, qnw, knw, qb, kb, vt);
    attn_kernel<<<dim3(TQ/128, BB*NQH), 256, 0, stream>>>(qb, kb, vt, ab);
    ogemm_kernel<<<dim3(32*32), 256, 0, stream>>>(ab, wo, out);
}